// Round 15
// baseline (3163.673 us; speedup 1.0000x reference)
//
#include <hip/hip_runtime.h>

#define NB 4
#define NPT 16384
#define NPOINT 1024
#define NSAMPLE 32

#define FPS_T 512 /* 8 waves; wave owns 2048 sorted points, 8 groups of 256 */

#define BQ_WAVES 4
#define CAP 896

// DPP wave-reduce helpers (verified on HW in r12/r14).
// max: bound_ctrl=true (0-fill safe: operands >= 0)
template <int CTRL>
__device__ __forceinline__ float dpp_fmax(float v) {
  const int s =
      __builtin_amdgcn_update_dpp(0, __float_as_int(v), CTRL, 0xf, 0xf, true);
  return fmaxf(v, __int_as_float(s));
}
// min variants: bound_ctrl=false (invalid lanes keep old value = v)
template <int CTRL>
__device__ __forceinline__ float dpp_fmin(float v) {
  const int s = __builtin_amdgcn_update_dpp(__float_as_int(v),
                                            __float_as_int(v), CTRL, 0xf, 0xf,
                                            false);
  const float o = __int_as_float(s);
  return fminf(v, o);
}
template <int CTRL>
__device__ __forceinline__ unsigned dpp_umin(unsigned v) {
  const unsigned s = (unsigned)__builtin_amdgcn_update_dpp((int)v, (int)v,
                                                           CTRL, 0xf, 0xf,
                                                           false);
  return s < v ? s : v;
}
#define DPP_CHAIN(fn, v)                                                      \
  v = fn<0x111>(v); /* row_shr:1  */                                          \
  v = fn<0x112>(v); /* row_shr:2  */                                          \
  v = fn<0x114>(v); /* row_shr:4  */                                          \
  v = fn<0x118>(v); /* row_shr:8  */                                          \
  v = fn<0x142>(v); /* row_bcast:15 */                                        \
  v = fn<0x143>(v); /* row_bcast:31 -> lane 63 holds reduction */

__device__ __forceinline__ unsigned part3(unsigned v) {
  return (v & 1u) | ((v & 2u) << 2) | ((v & 4u) << 4);
}

// ---------------------------------------------------------------------------
// Kernel 1: FPS with exact Morton-group pruning. One block (512 thr) / batch.
// Selection is bit-identical to the reference: d = ((dx*dx+dy*dy)+dz*dz)
// (contract off), argmax with lowest-ORIGINAL-index tie-break.
//
// r6..r14: full rescans cost ~4300 cyc/step regardless of state placement.
// This version sorts points by Morton cell once; each (wave,group) = 256
// consecutive sorted points with a precomputed AABB. A group is skipped
// exactly when (dist(boxctr,c)-r-slack)^2 >= max md in group: then every
// point satisfies d >= md, so md and the cached per-lane argmax candidate
// (value, origidx, z) are provably unchanged. Winner's group always rescans.
// ---------------------------------------------------------------------------
__global__ __launch_bounds__(FPS_T) void fps_kernel(
    const float* __restrict__ pos, float* __restrict__ new_pos) {
#pragma clang fp contract(off)
  const int b = blockIdx.x;
  const int tid = threadIdx.x;
  const int wid = tid >> 6;
  const int lane = tid & 63;
  const float* __restrict__ p = pos + (size_t)b * NPT * 3;

  // ---- LDS pool (max 144.8 KB live) ----------------------------------------
  __shared__ __align__(16) unsigned char lds[131072 + 1024 + 256 + 12288 + 32 + 96];
  float2* sxy = (float2*)lds;                       // [16384] by SORTED pos
  unsigned* sidx = (unsigned*)lds;                  // [16384] (setup only)
  unsigned* hist = (unsigned*)(lds + 65536);        // [512]   (setup only)
  unsigned* cursor = (unsigned*)(lds + 65536 + 2048); // [512] (setup only)
  float4* gbox = (float4*)(lds + 131072);           // [64] ctr.xyz, r
  float* gmd = (float*)(lds + 131072 + 1024);       // [64] max md per group
  float* clog = (float*)(lds + 131072 + 1024 + 256); // [3072]
  unsigned long long* red =
      (unsigned long long*)(lds + 131072 + 1024 + 256 + 12288); // [3]
  float* wzs = (float*)(lds + 131072 + 1024 + 256 + 12288 + 32); // [3][8]

  // ---- setup phase 1: histogram of Morton cells ----------------------------
  hist[tid] = 0u;
  __syncthreads();
  unsigned mort[32];
  {
    const float4* pf4 = (const float4*)(p + (size_t)tid * 96);
    float Xt[32], Yt[32], Zt[32];
#pragma unroll
    for (int k = 0; k < 8; ++k) {
      const float4 A = pf4[3 * k + 0];
      const float4 B = pf4[3 * k + 1];
      const float4 C = pf4[3 * k + 2];
      Xt[4 * k + 0] = A.x; Yt[4 * k + 0] = A.y; Zt[4 * k + 0] = A.z;
      Xt[4 * k + 1] = A.w; Yt[4 * k + 1] = B.x; Zt[4 * k + 1] = B.y;
      Xt[4 * k + 2] = B.z; Yt[4 * k + 2] = B.w; Zt[4 * k + 2] = C.x;
      Xt[4 * k + 3] = C.y; Yt[4 * k + 3] = C.z; Zt[4 * k + 3] = C.w;
    }
#pragma unroll
    for (int i = 0; i < 32; ++i) {
      int gx = (int)(Xt[i] * 8.0f); gx = gx > 7 ? 7 : (gx < 0 ? 0 : gx);
      int gy = (int)(Yt[i] * 8.0f); gy = gy > 7 ? 7 : (gy < 0 ? 0 : gy);
      int gz = (int)(Zt[i] * 8.0f); gz = gz > 7 ? 7 : (gz < 0 ? 0 : gz);
      mort[i] = part3((unsigned)gx) | (part3((unsigned)gy) << 1) |
                (part3((unsigned)gz) << 2);
      atomicAdd(&hist[mort[i]], 1u);
    }
  }
  __syncthreads();
  // ---- setup phase 2: exclusive prefix sum (Hillis-Steele) -----------------
  cursor[tid] = hist[tid];
  __syncthreads();
  for (int d = 1; d < 512; d <<= 1) {
    const unsigned v = (tid >= d) ? cursor[tid - d] : 0u;
    __syncthreads();
    cursor[tid] += v;
    __syncthreads();
  }
  cursor[tid] -= hist[tid]; // exclusive start
  __syncthreads();
  // ---- setup phase 3: scatter original indices into sorted order -----------
#pragma unroll
  for (int i = 0; i < 32; ++i) {
    const unsigned slot = atomicAdd(&cursor[mort[i]], 1u);
    sidx[slot] = (unsigned)(tid * 32 + i);
  }
  __syncthreads();
  // ---- setup phase 4: read my 32 sorted slots, then gather coords ----------
  const int base_sp = wid * 2048 + lane; // + g*256 + s*64
  unsigned IDX[32];
#pragma unroll
  for (int g = 0; g < 8; ++g)
#pragma unroll
    for (int s = 0; s < 4; ++s)
      IDX[g * 4 + s] = sidx[base_sp + g * 256 + s * 64];
  __syncthreads(); // sidx dead; sxy may now overwrite
  float Zc[32], Xs[32], Ys[32];
#pragma unroll
  for (int g = 0; g < 8; ++g)
#pragma unroll
    for (int s = 0; s < 4; ++s) {
      const unsigned oi = IDX[g * 4 + s];
      const float x = p[oi * 3 + 0];
      const float y = p[oi * 3 + 1];
      const float z = p[oi * 3 + 2];
      Xs[g * 4 + s] = x; Ys[g * 4 + s] = y; Zc[g * 4 + s] = z;
      sxy[base_sp + g * 256 + s * 64] = make_float2(x, y);
    }
  // ---- setup phase 5: per-group AABB ---------------------------------------
#pragma unroll
  for (int g = 0; g < 8; ++g) {
    float mnx = fminf(fminf(Xs[g * 4], Xs[g * 4 + 1]), fminf(Xs[g * 4 + 2], Xs[g * 4 + 3]));
    float mxx = fmaxf(fmaxf(Xs[g * 4], Xs[g * 4 + 1]), fmaxf(Xs[g * 4 + 2], Xs[g * 4 + 3]));
    float mny = fminf(fminf(Ys[g * 4], Ys[g * 4 + 1]), fminf(Ys[g * 4 + 2], Ys[g * 4 + 3]));
    float mxy = fmaxf(fmaxf(Ys[g * 4], Ys[g * 4 + 1]), fmaxf(Ys[g * 4 + 2], Ys[g * 4 + 3]));
    float mnz = fminf(fminf(Zc[g * 4], Zc[g * 4 + 1]), fminf(Zc[g * 4 + 2], Zc[g * 4 + 3]));
    float mxz = fmaxf(fmaxf(Zc[g * 4], Zc[g * 4 + 1]), fmaxf(Zc[g * 4 + 2], Zc[g * 4 + 3]));
    DPP_CHAIN(dpp_fmin, mnx) DPP_CHAIN(dpp_fmax, mxx)
    DPP_CHAIN(dpp_fmin, mny) DPP_CHAIN(dpp_fmax, mxy)
    DPP_CHAIN(dpp_fmin, mnz) DPP_CHAIN(dpp_fmax, mxz)
    if (lane == 63) {
      const float ex = mxx - mnx, ey = mxy - mny, ez = mxz - mnz;
      const float r = 0.5f * sqrtf(ex * ex + ey * ey + ez * ez) + 1e-4f;
      gbox[wid * 8 + g] =
          make_float4(0.5f * (mnx + mxx), 0.5f * (mny + mxy), 0.5f * (mnz + mxz), r);
      gmd[wid * 8 + g] = 1e10f;
    }
  }
  if (tid < 3) red[tid] = 0ull;
  __syncthreads();

  // ---- main loop -----------------------------------------------------------
  float md[32];
#pragma unroll
  for (int i = 0; i < 32; ++i) md[i] = 1e10f;
  float m4[8], z4[8];
  unsigned c4[8];
#pragma unroll
  for (int g = 0; g < 8; ++g) { m4[g] = -1.0f; c4[g] = 0u; z4[g] = 0.0f; }

  float cx = p[0], cy = p[1], cz = p[2]; // far = 0 initially

  for (int j = 0; j < NPOINT; ++j) {
    if (tid == 0) {
      clog[3 * j + 0] = cx;
      clog[3 * j + 1] = cy;
      clog[3 * j + 2] = cz;
    }
#pragma unroll
    for (int g = 0; g < 8; ++g) {
      const float4 bb = gbox[wid * 8 + g];
      const float gm = gmd[wid * 8 + g];
      const float ddx = bb.x - cx, ddy = bb.y - cy, ddz = bb.z - cz;
      const float q = ddx * ddx + ddy * ddy + ddz * ddz;
      const float t = sqrtf(q) - bb.w; // r already has +1e-4 slack
      const int skip = (t > 0.0f) && (t * t >= gm);
      if (!__builtin_amdgcn_readfirstlane(skip)) {
        float gmv = -1.0f, gz = 0.0f;
        unsigned gc = 0u;
#pragma unroll
        for (int s = 0; s < 4; ++s) {
          const float2 xy = sxy[base_sp + g * 256 + s * 64];
          const float dx = xy.x - cx;
          const float dy = xy.y - cy;
          const float dz = Zc[g * 4 + s] - cz;
          const float d = (dx * dx + dy * dy) + dz * dz;
          const float m = fminf(md[g * 4 + s], d);
          md[g * 4 + s] = m;
          if (m > gmv) {
            gmv = m;
            gc = (IDX[g * 4 + s] << 14) | (unsigned)(base_sp + g * 256 + s * 64);
            gz = Zc[g * 4 + s];
          }
        }
        m4[g] = gmv; c4[g] = gc; z4[g] = gz;
        float wmx = gmv;
        DPP_CHAIN(dpp_fmax, wmx)
        if (lane == 63) gmd[wid * 8 + g] = wmx;
      }
    }
    // per-lane best over 8 cached groups
    float bm = m4[0], bz = z4[0];
    unsigned bc = c4[0];
#pragma unroll
    for (int g = 1; g < 8; ++g)
      if (m4[g] > bm) { bm = m4[g]; bc = c4[g]; bz = z4[g]; }
    // wave value max
    float v = bm;
    DPP_CHAIN(dpp_fmax, v)
    const float wm =
        __int_as_float(__builtin_amdgcn_readlane(__float_as_int(v), 63));
    // among tied lanes pick min (origidx<<14|sp)
    unsigned cand = (bm == wm) ? bc : 0x0FFFFFFFu;
    DPP_CHAIN(dpp_umin, cand)
    const unsigned wc = (unsigned)__builtin_amdgcn_readlane((int)cand, 63);
    const unsigned long long tl = __ballot(bm == wm && bc == wc);
    const int wl = __ffsll((long long)tl) - 1;
    const float wbz =
        __int_as_float(__builtin_amdgcn_readlane(__float_as_int(bz), wl));
    // cross-wave: u64 key max = (max value, then min origidx)
    if (lane == 0) {
      atomicMax(&red[j % 3],
                ((unsigned long long)__float_as_uint(wm) << 32) | (unsigned)(~wc));
      wzs[(j % 3) * 8 + wid] = wbz;
    }
    __syncthreads();
    const unsigned long long w = red[j % 3];
    if (tid == 0) red[(j + 2) % 3] = 0ull;
    const unsigned wca = ~(unsigned)w;  // 28-bit (origidx<<14|sp)
    const unsigned sp = wca & 0x3FFFu;
    cz = wzs[(j % 3) * 8 + (sp >> 11)]; // winning wave's z
    const float2 cxy = sxy[sp];
    cx = cxy.x;
    cy = cxy.y;
  }

  __syncthreads();
  for (int k = tid; k < NPOINT * 3; k += FPS_T)
    new_pos[(size_t)b * NPOINT * 3 + k] = clog[k];
}

// ---------------------------------------------------------------------------
// Kernel 2: fused ball query + grouping + shared MLP + max-pool (unchanged).
// ---------------------------------------------------------------------------
__global__ __launch_bounds__(256) void bq_mlp_kernel(
    const float* __restrict__ pos, const float* __restrict__ x,
    const float* __restrict__ W1, const float* __restrict__ b1,
    const float* __restrict__ W2, const float* __restrict__ b2,
    const float* __restrict__ W3, const float* __restrict__ b3,
    const float* __restrict__ new_pos, float* __restrict__ out) {
#pragma clang fp contract(off)
  __shared__ __align__(16) float w1s[4 * 32];
  __shared__ __align__(16) float w2s[32 * 32];
  __shared__ __align__(16) float w3s[32 * 32];
  __shared__ float b1s[32], b2s[32], b3s[32];
  __shared__ unsigned long long list[BQ_WAVES][CAP];
  __shared__ int sel[BQ_WAVES][NSAMPLE];
  __shared__ unsigned cnt[BQ_WAVES];

  const int tid = threadIdx.x;
  const int wid = tid >> 6;
  const int lane = tid & 63;

  for (int i = tid; i < 128; i += 256) w1s[i] = W1[i];
  for (int i = tid; i < 1024; i += 256) {
    w2s[i] = W2[i];
    w3s[i] = W3[i];
  }
  if (tid < 32) {
    b1s[tid] = b1[tid];
    b2s[tid] = b2[tid];
    b3s[tid] = b3[tid];
  }
  if (lane == 0) cnt[wid] = 0u;
  __syncthreads();

  const int m_global = blockIdx.x * BQ_WAVES + wid; // 0..4095
  const int b = m_global >> 10;
  const float* __restrict__ p = pos + (size_t)b * NPT * 3;
  const float* __restrict__ xb = x + (size_t)b * NPT;

  const float cx = new_pos[(size_t)m_global * 3 + 0];
  const float cy = new_pos[(size_t)m_global * 3 + 1];
  const float cz = new_pos[(size_t)m_global * 3 + 2];
  const float snew = (cx * cx + cy * cy) + cz * cz;

  for (int it = 0; it < NPT / 256; ++it) {
    const int n0 = it * 256 + lane * 4;
    const float4* pf4 = (const float4*)(p + (size_t)n0 * 3);
    const float4 a = pf4[0];
    const float4 bq = pf4[1];
    const float4 c = pf4[2];
    float qx[4], qy[4], qz[4];
    qx[0] = a.x;  qy[0] = a.y;  qz[0] = a.z;
    qx[1] = a.w;  qy[1] = bq.x; qz[1] = bq.y;
    qx[2] = bq.z; qy[2] = bq.w; qz[2] = c.x;
    qx[3] = c.y;  qy[3] = c.z;  qz[3] = c.w;
#pragma unroll
    for (int t = 0; t < 4; ++t) {
      const float spos = (qx[t] * qx[t] + qy[t] * qy[t]) + qz[t] * qz[t];
      const float dot = (cx * qx[t] + cy * qy[t]) + cz * qz[t];
      const float d2 = (snew + spos) - 2.0f * dot; // reference op order
      if (d2 <= 0.01f) {
        const unsigned u = __float_as_uint(d2);
        const unsigned key = (u & 0x80000000u) ? ~u : (u | 0x80000000u);
        const unsigned li = atomicAdd(&cnt[wid], 1u);
        if (li < CAP)
          list[wid][li] = ((unsigned long long)key << 32) | (unsigned)(n0 + t);
      }
    }
  }
  __syncthreads();

  int c = (int)cnt[wid];
  if (c > CAP) c = CAP;
  const int nsel = c < NSAMPLE ? c : NSAMPLE;

  for (int i = lane; i < c; i += 64) {
    const unsigned long long ki = list[wid][i];
    int rank = 0;
    for (int jj = 0; jj < c; ++jj) rank += (list[wid][jj] < ki) ? 1 : 0;
    if (rank < NSAMPLE) sel[wid][rank] = (int)(unsigned)(ki & 0xFFFFFFFFull);
  }
  __syncthreads();

  const bool active = (lane < nsel);
  const int n = sel[wid][active ? lane : 0];

  const float gpx = p[n * 3 + 0];
  const float gpy = p[n * 3 + 1];
  const float gpz = p[n * 3 + 2];
  const float gxv = xb[n];

  const float h0 = gpx - cx, h1i = gpy - cy, h2i = gpz - cz, h3i = gxv;

  float h1[32];
#pragma unroll
  for (int o = 0; o < 32; ++o) {
    float a = b1s[o];
    a += h0 * w1s[0 * 32 + o];
    a += h1i * w1s[1 * 32 + o];
    a += h2i * w1s[2 * 32 + o];
    a += h3i * w1s[3 * 32 + o];
    h1[o] = fmaxf(a, 0.0f);
  }

  float acc[32];
#pragma unroll
  for (int o = 0; o < 32; ++o) acc[o] = b2s[o];
  for (int k = 0; k < 32; ++k) {
    const float hk = h1[k];
    const float4* row = (const float4*)&w2s[k * 32];
#pragma unroll
    for (int q = 0; q < 8; ++q) {
      const float4 ww = row[q];
      acc[4 * q + 0] += hk * ww.x;
      acc[4 * q + 1] += hk * ww.y;
      acc[4 * q + 2] += hk * ww.z;
      acc[4 * q + 3] += hk * ww.w;
    }
  }
#pragma unroll
  for (int o = 0; o < 32; ++o) h1[o] = fmaxf(acc[o], 0.0f);

#pragma unroll
  for (int o = 0; o < 32; ++o) acc[o] = b3s[o];
  for (int k = 0; k < 32; ++k) {
    const float hk = h1[k];
    const float4* row = (const float4*)&w3s[k * 32];
#pragma unroll
    for (int q = 0; q < 8; ++q) {
      const float4 ww = row[q];
      acc[4 * q + 0] += hk * ww.x;
      acc[4 * q + 1] += hk * ww.y;
      acc[4 * q + 2] += hk * ww.z;
      acc[4 * q + 3] += hk * ww.w;
    }
  }
#pragma unroll
  for (int o = 0; o < 32; ++o)
    acc[o] = active ? fmaxf(acc[o], 0.0f) : -INFINITY;

#pragma unroll
  for (int mask = 1; mask <= 16; mask <<= 1) {
#pragma unroll
    for (int o = 0; o < 32; ++o)
      acc[o] = fmaxf(acc[o], __shfl_xor(acc[o], mask, 64));
  }

  if (lane == 0) {
    float4* o4 = (float4*)(out + (size_t)m_global * 32);
#pragma unroll
    for (int q = 0; q < 8; ++q)
      o4[q] = make_float4(acc[4 * q + 0], acc[4 * q + 1], acc[4 * q + 2],
                          acc[4 * q + 3]);
  }
}

// ---------------------------------------------------------------------------
extern "C" void kernel_launch(void* const* d_in, const int* in_sizes, int n_in,
                              void* d_out, int out_size, void* d_ws,
                              size_t ws_size, hipStream_t stream) {
  const float* pos = (const float*)d_in[0];
  const float* x = (const float*)d_in[1];
  const float* W1 = (const float*)d_in[2];
  const float* b1 = (const float*)d_in[3];
  const float* W2 = (const float*)d_in[4];
  const float* b2 = (const float*)d_in[5];
  const float* W3 = (const float*)d_in[6];
  const float* b3 = (const float*)d_in[7];
  float* out = (float*)d_out;
  float* new_pos = (float*)d_ws; // NB*NPOINT*3 floats = 48 KiB

  fps_kernel<<<NB, FPS_T, 0, stream>>>(pos, new_pos);
  bq_mlp_kernel<<<(NB * NPOINT) / BQ_WAVES, 256, 0, stream>>>(
      pos, x, W1, b1, W2, b2, W3, b3, new_pos, out);
}

// Round 16
// 3051.884 us; speedup vs baseline: 1.0366x; 1.0366x over previous
//
#include <hip/hip_runtime.h>

#define NB 4
#define NPT 16384
#define NPOINT 1024
#define NSAMPLE 32

#define FPS_T 256
#define FPS_PPT 64 /* idx = tid*64 + i */

#define BQ_WAVES 4
#define CAP 896

template <int CTRL>
__device__ __forceinline__ float dpp_fmax(float v) {
  const int s =
      __builtin_amdgcn_update_dpp(0, __float_as_int(v), CTRL, 0xf, 0xf, true);
  return fmaxf(v, __int_as_float(s));
}
#define DPP_MAX_CHAIN(v)                                                      \
  v = dpp_fmax<0x111>(v);                                                     \
  v = dpp_fmax<0x112>(v);                                                     \
  v = dpp_fmax<0x114>(v);                                                     \
  v = dpp_fmax<0x118>(v);                                                     \
  v = dpp_fmax<0x142>(v);                                                     \
  v = dpp_fmax<0x143>(v); /* lane 63 holds wave max */

#define REP64(M)                                                              \
  M(0) M(1) M(2) M(3) M(4) M(5) M(6) M(7) M(8) M(9) M(10) M(11) M(12) M(13)  \
  M(14) M(15) M(16) M(17) M(18) M(19) M(20) M(21) M(22) M(23) M(24) M(25)    \
  M(26) M(27) M(28) M(29) M(30) M(31) M(32) M(33) M(34) M(35) M(36) M(37)    \
  M(38) M(39) M(40) M(41) M(42) M(43) M(44) M(45) M(46) M(47) M(48) M(49)    \
  M(50) M(51) M(52) M(53) M(54) M(55) M(56) M(57) M(58) M(59) M(60) M(61)    \
  M(62) M(63)

// ---------------------------------------------------------------------------
// Kernel 1: farthest point sampling. One block (256 thr / 4 waves) per batch.
// Bit-exact with the JAX reference: d = ((dx*dx+dy*dy)+dz*dz), contract off,
// argmax with first-index (lowest global idx) tie-break (idx = tid*64+i).
//
// r6-r15 forensics: every prior variant re-read all 16K coords per step
// (compiler spilled private arrays/scalars and reloaded from LDS/L2; VGPR=88
// tell). This version: 64 pts/thread on 256 threads with launch_bounds(256,1)
// -> 512-VGPR budget, coords+md as 256 NAMED scalars; asm pins INSIDE the
// loop make stale-copy reloads illegal; no LDS coordinate stash exists.
// Scan is pure VALU. Winner xyz tracked via cndmask, broadcast via readlane
// + tiny LDS. Centroids logged to LDS, flushed once (no vmcnt drain in loop).
// ---------------------------------------------------------------------------
__global__ __launch_bounds__(FPS_T, 1) void fps_kernel(
    const float* __restrict__ pos, float* __restrict__ new_pos) {
#pragma clang fp contract(off)
  const int b = blockIdx.x;
  const int tid = threadIdx.x;
  const int wid = tid >> 6;
  const int lane = tid & 63;
  const float* __restrict__ p = pos + (size_t)b * NPT * 3;

  __shared__ float clog[NPOINT * 3];    // 12 KiB
  __shared__ unsigned long long red[3]; // (bits(max)<<32)|~idx
  __shared__ float wxs[3][4], wys[3][4], wzs[3][4];

#define DECLPT(i) float X##i, Y##i, Z##i, MD##i;
  REP64(DECLPT)

  // load 64 consecutive points (768B) per thread via float4 -> named scalars
  {
    const float4* pf4 = (const float4*)(p + (size_t)tid * (FPS_PPT * 3));
#define LODG(g, p0, p1, p2, p3)                                               \
  {                                                                           \
    const float4 A = pf4[3 * (g)], B = pf4[3 * (g) + 1], C = pf4[3 * (g) + 2];\
    X##p0 = A.x; Y##p0 = A.y; Z##p0 = A.z;                                    \
    X##p1 = A.w; Y##p1 = B.x; Z##p1 = B.y;                                    \
    X##p2 = B.z; Y##p2 = B.w; Z##p2 = C.x;                                    \
    X##p3 = C.y; Y##p3 = C.z; Z##p3 = C.w;                                    \
  }
    LODG(0, 0, 1, 2, 3)
    LODG(1, 4, 5, 6, 7)
    LODG(2, 8, 9, 10, 11)
    LODG(3, 12, 13, 14, 15)
    LODG(4, 16, 17, 18, 19)
    LODG(5, 20, 21, 22, 23)
    LODG(6, 24, 25, 26, 27)
    LODG(7, 28, 29, 30, 31)
    LODG(8, 32, 33, 34, 35)
    LODG(9, 36, 37, 38, 39)
    LODG(10, 40, 41, 42, 43)
    LODG(11, 44, 45, 46, 47)
    LODG(12, 48, 49, 50, 51)
    LODG(13, 52, 53, 54, 55)
    LODG(14, 56, 57, 58, 59)
    LODG(15, 60, 61, 62, 63)
  }
#define INITMD(i) MD##i = 1e10f;
  REP64(INITMD)

  if (tid < 3) red[tid] = 0ull;
  __syncthreads();

  float cx = p[0], cy = p[1], cz = p[2]; // far = 0 initially

  for (int j = 0; j < NPOINT; ++j) {
    // pins: values opaque each iteration -> reload-from-source is illegal,
    // compiler must keep X/Y/Z live (512-VGPR budget at 1 wave/SIMD)
#define PIN3(i) asm volatile("" : "+v"(X##i), "+v"(Y##i), "+v"(Z##i));
    REP64(PIN3)

    if (tid == 0) { // LDS log only -- no global store in loop
      clog[3 * j + 0] = cx;
      clog[3 * j + 1] = cy;
      clog[3 * j + 2] = cz;
    }
    // ---- distance pass (pure VALU) + per-thread argmax (first-i on ties) ---
    float bm = -1.0f;
    int bi = 0;
    float bx = 0.0f, by = 0.0f, bz = 0.0f;
#define SCAN(i)                                                               \
  {                                                                           \
    const float dx = X##i - cx;                                               \
    const float dy = Y##i - cy;                                               \
    const float dz = Z##i - cz;                                               \
    const float d = (dx * dx + dy * dy) + dz * dz;                            \
    const float m = fminf(MD##i, d);                                          \
    MD##i = m;                                                                \
    if (m > bm) {                                                             \
      bm = m;                                                                 \
      bi = i;                                                                 \
      bx = X##i;                                                              \
      by = Y##i;                                                              \
      bz = Z##i;                                                              \
    }                                                                         \
  }
    REP64(SCAN)
    // ---- in-wave argmax: DPP max chain + ballot + readlane -----------------
    float v = bm;
    DPP_MAX_CHAIN(v)
    const float wm =
        __int_as_float(__builtin_amdgcn_readlane(__float_as_int(v), 63));
    const unsigned long long tied = __ballot(bm == wm);
    const int wl = __ffsll((long long)tied) - 1; // lowest tied lane = min idx
    const int wbi = __builtin_amdgcn_readlane(bi, wl);
    const float wbx =
        __int_as_float(__builtin_amdgcn_readlane(__float_as_int(bx), wl));
    const float wby =
        __int_as_float(__builtin_amdgcn_readlane(__float_as_int(by), wl));
    const float wbz =
        __int_as_float(__builtin_amdgcn_readlane(__float_as_int(bz), wl));
    const int widx = ((wid << 6) + wl) * FPS_PPT + wbi; // global orig index
    // ---- cross-wave: one LDS u64 atomicMax + winner-xyz stash --------------
    if (lane == 0) {
      const unsigned long long key =
          ((unsigned long long)__float_as_uint(wm) << 32) |
          (unsigned)(~widx);
      atomicMax(&red[j % 3], key);
      wxs[j % 3][wid] = wbx;
      wys[j % 3][wid] = wby;
      wzs[j % 3][wid] = wbz;
    }
    __syncthreads();
    const unsigned long long w = red[j % 3];
    if (tid == 0) red[(j + 2) % 3] = 0ull; // 2 barriers from any prior use
    const unsigned nf = ~(unsigned)w;      // winning global idx
    const int wv = (int)(nf >> 12);        // winning wave (4096 idx per wave)
    cx = wxs[j % 3][wv];
    cy = wys[j % 3][wv];
    cz = wzs[j % 3][wv];
  }

  __syncthreads();
  // flush centroid log to global, coalesced
  for (int k = tid; k < NPOINT * 3; k += FPS_T)
    new_pos[(size_t)b * NPOINT * 3 + k] = clog[k];
}

// ---------------------------------------------------------------------------
// Kernel 2: fused ball query + grouping + shared MLP + max-pool (unchanged,
// passed 6x). One wave per centroid, 4 waves per block.
// ---------------------------------------------------------------------------
__global__ __launch_bounds__(256) void bq_mlp_kernel(
    const float* __restrict__ pos, const float* __restrict__ x,
    const float* __restrict__ W1, const float* __restrict__ b1,
    const float* __restrict__ W2, const float* __restrict__ b2,
    const float* __restrict__ W3, const float* __restrict__ b3,
    const float* __restrict__ new_pos, float* __restrict__ out) {
#pragma clang fp contract(off)
  __shared__ __align__(16) float w1s[4 * 32];
  __shared__ __align__(16) float w2s[32 * 32];
  __shared__ __align__(16) float w3s[32 * 32];
  __shared__ float b1s[32], b2s[32], b3s[32];
  __shared__ unsigned long long list[BQ_WAVES][CAP];
  __shared__ int sel[BQ_WAVES][NSAMPLE];
  __shared__ unsigned cnt[BQ_WAVES];

  const int tid = threadIdx.x;
  const int wid = tid >> 6;
  const int lane = tid & 63;

  for (int i = tid; i < 128; i += 256) w1s[i] = W1[i];
  for (int i = tid; i < 1024; i += 256) {
    w2s[i] = W2[i];
    w3s[i] = W3[i];
  }
  if (tid < 32) {
    b1s[tid] = b1[tid];
    b2s[tid] = b2[tid];
    b3s[tid] = b3[tid];
  }
  if (lane == 0) cnt[wid] = 0u;
  __syncthreads();

  const int m_global = blockIdx.x * BQ_WAVES + wid; // 0..4095
  const int b = m_global >> 10;
  const float* __restrict__ p = pos + (size_t)b * NPT * 3;
  const float* __restrict__ xb = x + (size_t)b * NPT;

  const float cx = new_pos[(size_t)m_global * 3 + 0];
  const float cy = new_pos[(size_t)m_global * 3 + 1];
  const float cz = new_pos[(size_t)m_global * 3 + 2];
  const float snew = (cx * cx + cy * cy) + cz * cz;

  for (int it = 0; it < NPT / 256; ++it) {
    const int n0 = it * 256 + lane * 4;
    const float4* pf4 = (const float4*)(p + (size_t)n0 * 3);
    const float4 a = pf4[0];
    const float4 bq = pf4[1];
    const float4 c = pf4[2];
    float qx[4], qy[4], qz[4];
    qx[0] = a.x;  qy[0] = a.y;  qz[0] = a.z;
    qx[1] = a.w;  qy[1] = bq.x; qz[1] = bq.y;
    qx[2] = bq.z; qy[2] = bq.w; qz[2] = c.x;
    qx[3] = c.y;  qy[3] = c.z;  qz[3] = c.w;
#pragma unroll
    for (int t = 0; t < 4; ++t) {
      const float spos = (qx[t] * qx[t] + qy[t] * qy[t]) + qz[t] * qz[t];
      const float dot = (cx * qx[t] + cy * qy[t]) + cz * qz[t];
      const float d2 = (snew + spos) - 2.0f * dot; // reference op order
      if (d2 <= 0.01f) {
        const unsigned u = __float_as_uint(d2);
        const unsigned key = (u & 0x80000000u) ? ~u : (u | 0x80000000u);
        const unsigned li = atomicAdd(&cnt[wid], 1u);
        if (li < CAP)
          list[wid][li] = ((unsigned long long)key << 32) | (unsigned)(n0 + t);
      }
    }
  }
  __syncthreads();

  int c = (int)cnt[wid];
  if (c > CAP) c = CAP;
  const int nsel = c < NSAMPLE ? c : NSAMPLE;

  for (int i = lane; i < c; i += 64) {
    const unsigned long long ki = list[wid][i];
    int rank = 0;
    for (int jj = 0; jj < c; ++jj) rank += (list[wid][jj] < ki) ? 1 : 0;
    if (rank < NSAMPLE) sel[wid][rank] = (int)(unsigned)(ki & 0xFFFFFFFFull);
  }
  __syncthreads();

  const bool active = (lane < nsel);
  const int n = sel[wid][active ? lane : 0];

  const float gpx = p[n * 3 + 0];
  const float gpy = p[n * 3 + 1];
  const float gpz = p[n * 3 + 2];
  const float gxv = xb[n];

  const float h0 = gpx - cx, h1i = gpy - cy, h2i = gpz - cz, h3i = gxv;

  float h1[32];
#pragma unroll
  for (int o = 0; o < 32; ++o) {
    float a = b1s[o];
    a += h0 * w1s[0 * 32 + o];
    a += h1i * w1s[1 * 32 + o];
    a += h2i * w1s[2 * 32 + o];
    a += h3i * w1s[3 * 32 + o];
    h1[o] = fmaxf(a, 0.0f);
  }

  float acc[32];
#pragma unroll
  for (int o = 0; o < 32; ++o) acc[o] = b2s[o];
  for (int k = 0; k < 32; ++k) {
    const float hk = h1[k];
    const float4* row = (const float4*)&w2s[k * 32];
#pragma unroll
    for (int q = 0; q < 8; ++q) {
      const float4 ww = row[q];
      acc[4 * q + 0] += hk * ww.x;
      acc[4 * q + 1] += hk * ww.y;
      acc[4 * q + 2] += hk * ww.z;
      acc[4 * q + 3] += hk * ww.w;
    }
  }
#pragma unroll
  for (int o = 0; o < 32; ++o) h1[o] = fmaxf(acc[o], 0.0f);

#pragma unroll
  for (int o = 0; o < 32; ++o) acc[o] = b3s[o];
  for (int k = 0; k < 32; ++k) {
    const float hk = h1[k];
    const float4* row = (const float4*)&w3s[k * 32];
#pragma unroll
    for (int q = 0; q < 8; ++q) {
      const float4 ww = row[q];
      acc[4 * q + 0] += hk * ww.x;
      acc[4 * q + 1] += hk * ww.y;
      acc[4 * q + 2] += hk * ww.z;
      acc[4 * q + 3] += hk * ww.w;
    }
  }
#pragma unroll
  for (int o = 0; o < 32; ++o)
    acc[o] = active ? fmaxf(acc[o], 0.0f) : -INFINITY;

#pragma unroll
  for (int mask = 1; mask <= 16; mask <<= 1) {
#pragma unroll
    for (int o = 0; o < 32; ++o)
      acc[o] = fmaxf(acc[o], __shfl_xor(acc[o], mask, 64));
  }

  if (lane == 0) {
    float4* o4 = (float4*)(out + (size_t)m_global * 32);
#pragma unroll
    for (int q = 0; q < 8; ++q)
      o4[q] = make_float4(acc[4 * q + 0], acc[4 * q + 1], acc[4 * q + 2],
                          acc[4 * q + 3]);
  }
}

// ---------------------------------------------------------------------------
extern "C" void kernel_launch(void* const* d_in, const int* in_sizes, int n_in,
                              void* d_out, int out_size, void* d_ws,
                              size_t ws_size, hipStream_t stream) {
  const float* pos = (const float*)d_in[0];
  const float* x = (const float*)d_in[1];
  const float* W1 = (const float*)d_in[2];
  const float* b1 = (const float*)d_in[3];
  const float* W2 = (const float*)d_in[4];
  const float* b2 = (const float*)d_in[5];
  const float* W3 = (const float*)d_in[6];
  const float* b3 = (const float*)d_in[7];
  float* out = (float*)d_out;
  float* new_pos = (float*)d_ws; // NB*NPOINT*3 floats = 48 KiB

  fps_kernel<<<NB, FPS_T, 0, stream>>>(pos, new_pos);
  bq_mlp_kernel<<<(NB * NPOINT) / BQ_WAVES, 256, 0, stream>>>(
      pos, x, W1, b1, W2, b2, W3, b3, new_pos, out);
}

// Round 17
// 2115.232 us; speedup vs baseline: 1.4957x; 1.4428x over previous
//
#include <hip/hip_runtime.h>

#define NB 4
#define NPT 16384
#define NPOINT 1024
#define NSAMPLE 32

#define FPS_T 1024 /* 16 waves; wave owns 1024 sorted pts = 4 groups x 256 */

#define BQ_WAVES 4
#define CAP 896

// DPP wave-reduce helpers (HW-verified r12/r14/r15).
template <int CTRL>
__device__ __forceinline__ float dpp_fmax(float v) {
  const int s =
      __builtin_amdgcn_update_dpp(0, __float_as_int(v), CTRL, 0xf, 0xf, true);
  return fmaxf(v, __int_as_float(s));
}
template <int CTRL>
__device__ __forceinline__ float dpp_fmin(float v) {
  const int s = __builtin_amdgcn_update_dpp(__float_as_int(v),
                                            __float_as_int(v), CTRL, 0xf, 0xf,
                                            false);
  return fminf(v, __int_as_float(s));
}
template <int CTRL>
__device__ __forceinline__ unsigned dpp_umin(unsigned v) {
  const unsigned s = (unsigned)__builtin_amdgcn_update_dpp((int)v, (int)v,
                                                           CTRL, 0xf, 0xf,
                                                           false);
  return s < v ? s : v;
}
#define DPP_CHAIN(fn, v)                                                      \
  v = fn<0x111>(v);                                                           \
  v = fn<0x112>(v);                                                           \
  v = fn<0x114>(v);                                                           \
  v = fn<0x118>(v);                                                           \
  v = fn<0x142>(v);                                                           \
  v = fn<0x143>(v); /* lane 63 holds reduction */

__device__ __forceinline__ unsigned part3(unsigned v) {
  return (v & 1u) | ((v & 2u) << 2) | ((v & 4u) << 4);
}

// ---------------------------------------------------------------------------
// Kernel 1: FPS with exact Morton-group pruning, parallel-test edition.
// One block (1024 thr / 16 waves) per batch. Bit-identical selection to the
// reference (d = ((dx*dx+dy*dy)+dz*dz), contract off, min-origidx ties).
//
// r15 failed on SERIALIZATION (per-group LDS-load+sqrt+branch chains), not on
// prune rate (VALUBusy 0.82). Here: (A) lane g tests group g in parallel ->
// one ballot -> uniform mask; group loop pays only an sgpr bit-test. (B)
// scans of non-pruned groups. (C) branchless batched gmd recompute for all
// groups (unscanned rewrite the same value). (D) r15's verified reduce.
// 16 pts/thread keeps core state at 48 regs (r2-proven promotable size).
// ---------------------------------------------------------------------------
__global__ __launch_bounds__(FPS_T) void fps_kernel(
    const float* __restrict__ pos, float* __restrict__ new_pos) {
#pragma clang fp contract(off)
  const int b = blockIdx.x;
  const int tid = threadIdx.x;
  const int wid = tid >> 6;
  const int lane = tid & 63;
  const float* __restrict__ p = pos + (size_t)b * NPT * 3;

  // ---- LDS pool, 144864 B ≈ 141.5 KB --------------------------------------
  __shared__ __align__(16) unsigned char lds[144864];
  float2* sxy = (float2*)lds;                        // [16384] sorted (x,y)
  unsigned* sidx = (unsigned*)lds;                   // [16384] setup overlay
  unsigned* hist = (unsigned*)(lds + 65536);         // [512] setup
  unsigned* cursor = (unsigned*)(lds + 67584);       // [512] setup
  float4* gbox = (float4*)(lds + 131072);            // [64] ctr.xyz, r
  float* gmd = (float*)(lds + 132096);               // [64] max md per group
  float* clog = (float*)(lds + 132352);              // [3072]
  unsigned long long* red = (unsigned long long*)(lds + 144640); // [3]
  float* wzs = (float*)(lds + 144672);               // [3][16]

  // ---- setup 1: Morton histogram (512 cells of 0.125^3) --------------------
  if (tid < 512) hist[tid] = 0u;
  __syncthreads();
  unsigned mort[16];
  {
    const float4* pf4 = (const float4*)p + (size_t)tid * 12;
    float Xt[16], Yt[16], Zt[16];
#pragma unroll
    for (int k = 0; k < 4; ++k) {
      const float4 A = pf4[3 * k + 0];
      const float4 B = pf4[3 * k + 1];
      const float4 C = pf4[3 * k + 2];
      Xt[4 * k + 0] = A.x; Yt[4 * k + 0] = A.y; Zt[4 * k + 0] = A.z;
      Xt[4 * k + 1] = A.w; Yt[4 * k + 1] = B.x; Zt[4 * k + 1] = B.y;
      Xt[4 * k + 2] = B.z; Yt[4 * k + 2] = B.w; Zt[4 * k + 2] = C.x;
      Xt[4 * k + 3] = C.y; Yt[4 * k + 3] = C.z; Zt[4 * k + 3] = C.w;
    }
#pragma unroll
    for (int i = 0; i < 16; ++i) {
      int gx = (int)(Xt[i] * 8.0f); gx = gx > 7 ? 7 : (gx < 0 ? 0 : gx);
      int gy = (int)(Yt[i] * 8.0f); gy = gy > 7 ? 7 : (gy < 0 ? 0 : gy);
      int gz = (int)(Zt[i] * 8.0f); gz = gz > 7 ? 7 : (gz < 0 ? 0 : gz);
      mort[i] = part3((unsigned)gx) | (part3((unsigned)gy) << 1) |
                (part3((unsigned)gz) << 2);
      atomicAdd(&hist[mort[i]], 1u);
    }
  }
  __syncthreads();
  // ---- setup 2: exclusive prefix sum over 512 cells ------------------------
  if (tid < 512) cursor[tid] = hist[tid];
  __syncthreads();
  for (int d = 1; d < 512; d <<= 1) {
    unsigned v = 0u;
    if (tid < 512 && tid >= d) v = cursor[tid - d];
    __syncthreads();
    if (tid < 512) cursor[tid] += v;
    __syncthreads();
  }
  if (tid < 512) cursor[tid] -= hist[tid];
  __syncthreads();
  // ---- setup 3: scatter original indices into sorted order -----------------
#pragma unroll
  for (int i = 0; i < 16; ++i) {
    const unsigned slot = atomicAdd(&cursor[mort[i]], 1u);
    sidx[slot] = (unsigned)(tid * 16 + i);
  }
  __syncthreads();
  // ---- setup 4: read my 16 sorted slots, gather coords ---------------------
  const int base_sp = wid * 1024 + lane; // + g*256 + s*64
  unsigned IDX[16];
#pragma unroll
  for (int g = 0; g < 4; ++g)
#pragma unroll
    for (int s = 0; s < 4; ++s)
      IDX[g * 4 + s] = sidx[base_sp + g * 256 + s * 64];
  __syncthreads(); // sidx/hist/cursor dead; sxy may overwrite
  float Zc[16], Xs[16], Ys[16];
#pragma unroll
  for (int g = 0; g < 4; ++g)
#pragma unroll
    for (int s = 0; s < 4; ++s) {
      const unsigned oi = IDX[g * 4 + s];
      const float x = p[oi * 3 + 0];
      const float y = p[oi * 3 + 1];
      const float z = p[oi * 3 + 2];
      Xs[g * 4 + s] = x; Ys[g * 4 + s] = y; Zc[g * 4 + s] = z;
      sxy[base_sp + g * 256 + s * 64] = make_float2(x, y);
    }
  // ---- setup 5: per-group AABB (center, half-diagonal + slack) -------------
#pragma unroll
  for (int g = 0; g < 4; ++g) {
    float mnx = fminf(fminf(Xs[g * 4], Xs[g * 4 + 1]), fminf(Xs[g * 4 + 2], Xs[g * 4 + 3]));
    float mxx = fmaxf(fmaxf(Xs[g * 4], Xs[g * 4 + 1]), fmaxf(Xs[g * 4 + 2], Xs[g * 4 + 3]));
    float mny = fminf(fminf(Ys[g * 4], Ys[g * 4 + 1]), fminf(Ys[g * 4 + 2], Ys[g * 4 + 3]));
    float mxy = fmaxf(fmaxf(Ys[g * 4], Ys[g * 4 + 1]), fmaxf(Ys[g * 4 + 2], Ys[g * 4 + 3]));
    float mnz = fminf(fminf(Zc[g * 4], Zc[g * 4 + 1]), fminf(Zc[g * 4 + 2], Zc[g * 4 + 3]));
    float mxz = fmaxf(fmaxf(Zc[g * 4], Zc[g * 4 + 1]), fmaxf(Zc[g * 4 + 2], Zc[g * 4 + 3]));
    DPP_CHAIN(dpp_fmin, mnx) DPP_CHAIN(dpp_fmax, mxx)
    DPP_CHAIN(dpp_fmin, mny) DPP_CHAIN(dpp_fmax, mxy)
    DPP_CHAIN(dpp_fmin, mnz) DPP_CHAIN(dpp_fmax, mxz)
    if (lane == 63) {
      const float ex = mxx - mnx, ey = mxy - mny, ez = mxz - mnz;
      const float r = 0.5f * sqrtf(ex * ex + ey * ey + ez * ez) + 1e-4f;
      gbox[wid * 4 + g] =
          make_float4(0.5f * (mnx + mxx), 0.5f * (mny + mxy), 0.5f * (mnz + mxz), r);
      gmd[wid * 4 + g] = 1e10f;
    }
  }
  if (tid < 3) red[tid] = 0ull;
  __syncthreads();

  // ---- main loop -----------------------------------------------------------
  float md[16];
#pragma unroll
  for (int i = 0; i < 16; ++i) md[i] = 1e10f;
  float m4[4], z4[4];
  unsigned c4[4];
#pragma unroll
  for (int g = 0; g < 4; ++g) { m4[g] = -1.0f; c4[g] = 0u; z4[g] = 0.0f; }

  float cx = p[0], cy = p[1], cz = p[2]; // far = 0 initially

  for (int j = 0; j < NPOINT; ++j) {
    if (tid == 0) {
      clog[3 * j + 0] = cx;
      clog[3 * j + 1] = cy;
      clog[3 * j + 2] = cz;
    }
    // ---- A: parallel prune tests (lane g tests group g), one ballot --------
    int keep = 0;
    if (lane < 4) {
      const float4 bb = gbox[wid * 4 + lane];
      const float gm = gmd[wid * 4 + lane];
      const float ddx = bb.x - cx, ddy = bb.y - cy, ddz = bb.z - cz;
      const float q = ddx * ddx + ddy * ddy + ddz * ddz;
      const float t = sqrtf(q) - bb.w; // r has +1e-4 slack: skip is EXACT
      keep = !((t > 0.0f) && (t * t >= gm));
    }
    const unsigned mask = (unsigned)__ballot(keep != 0) & 0xFu; // uniform
    // ---- B: scan kept groups (sgpr bit-test only per group) ----------------
#pragma unroll
    for (int g = 0; g < 4; ++g) {
      if (mask & (1u << g)) {
        float gmv = -1.0f, gz = 0.0f;
        unsigned gc = 0u;
#pragma unroll
        for (int s = 0; s < 4; ++s) {
          const float2 xy = sxy[base_sp + g * 256 + s * 64];
          const float dx = xy.x - cx;
          const float dy = xy.y - cy;
          const float dz = Zc[g * 4 + s] - cz;
          const float d = (dx * dx + dy * dy) + dz * dz;
          const float m = fminf(md[g * 4 + s], d);
          md[g * 4 + s] = m;
          if (m > gmv) {
            gmv = m;
            gc = (IDX[g * 4 + s] << 14) |
                 (unsigned)(base_sp + g * 256 + s * 64);
            gz = Zc[g * 4 + s];
          }
        }
        m4[g] = gmv; c4[g] = gc; z4[g] = gz;
      }
    }
    // ---- C: branchless batched gmd recompute (all groups) ------------------
#pragma unroll
    for (int g = 0; g < 4; ++g) {
      float v = m4[g];
      DPP_CHAIN(dpp_fmax, v)
      if (lane == 63) gmd[wid * 4 + g] = v;
    }
    // ---- D: winner selection (r15-verified path) ---------------------------
    float bm = m4[0], bz = z4[0];
    unsigned bc = c4[0];
#pragma unroll
    for (int g = 1; g < 4; ++g)
      if (m4[g] > bm) { bm = m4[g]; bc = c4[g]; bz = z4[g]; }
    float v = bm;
    DPP_CHAIN(dpp_fmax, v)
    const float wm =
        __int_as_float(__builtin_amdgcn_readlane(__float_as_int(v), 63));
    unsigned cand = (bm == wm) ? bc : 0x0FFFFFFFu;
    DPP_CHAIN(dpp_umin, cand)
    const unsigned wc = (unsigned)__builtin_amdgcn_readlane((int)cand, 63);
    const unsigned long long tl = __ballot(bm == wm && bc == wc);
    const int wl = __ffsll((long long)tl) - 1;
    const float wbz =
        __int_as_float(__builtin_amdgcn_readlane(__float_as_int(bz), wl));
    if (lane == 0) {
      atomicMax(&red[j % 3],
                ((unsigned long long)__float_as_uint(wm) << 32) |
                    (unsigned)(~wc));
      wzs[(j % 3) * 16 + wid] = wbz;
    }
    __syncthreads();
    const unsigned long long w = red[j % 3];
    if (tid == 0) red[(j + 2) % 3] = 0ull;
    const unsigned wca = ~(unsigned)w; // (origidx<<14|sp)
    const unsigned sp = wca & 0x3FFFu;
    cz = wzs[(j % 3) * 16 + (sp >> 10)]; // winning wave's z
    const float2 cxy = sxy[sp];
    cx = cxy.x;
    cy = cxy.y;
  }

  __syncthreads();
  for (int k = tid; k < NPOINT * 3; k += FPS_T)
    new_pos[(size_t)b * NPOINT * 3 + k] = clog[k];
}

// ---------------------------------------------------------------------------
// Kernel 2: fused ball query + grouping + shared MLP + max-pool (unchanged,
// passed 8x). One wave per centroid, 4 waves per block.
// ---------------------------------------------------------------------------
__global__ __launch_bounds__(256) void bq_mlp_kernel(
    const float* __restrict__ pos, const float* __restrict__ x,
    const float* __restrict__ W1, const float* __restrict__ b1,
    const float* __restrict__ W2, const float* __restrict__ b2,
    const float* __restrict__ W3, const float* __restrict__ b3,
    const float* __restrict__ new_pos, float* __restrict__ out) {
#pragma clang fp contract(off)
  __shared__ __align__(16) float w1s[4 * 32];
  __shared__ __align__(16) float w2s[32 * 32];
  __shared__ __align__(16) float w3s[32 * 32];
  __shared__ float b1s[32], b2s[32], b3s[32];
  __shared__ unsigned long long list[BQ_WAVES][CAP];
  __shared__ int sel[BQ_WAVES][NSAMPLE];
  __shared__ unsigned cnt[BQ_WAVES];

  const int tid = threadIdx.x;
  const int wid = tid >> 6;
  const int lane = tid & 63;

  for (int i = tid; i < 128; i += 256) w1s[i] = W1[i];
  for (int i = tid; i < 1024; i += 256) {
    w2s[i] = W2[i];
    w3s[i] = W3[i];
  }
  if (tid < 32) {
    b1s[tid] = b1[tid];
    b2s[tid] = b2[tid];
    b3s[tid] = b3[tid];
  }
  if (lane == 0) cnt[wid] = 0u;
  __syncthreads();

  const int m_global = blockIdx.x * BQ_WAVES + wid; // 0..4095
  const int b = m_global >> 10;
  const float* __restrict__ p = pos + (size_t)b * NPT * 3;
  const float* __restrict__ xb = x + (size_t)b * NPT;

  const float cx = new_pos[(size_t)m_global * 3 + 0];
  const float cy = new_pos[(size_t)m_global * 3 + 1];
  const float cz = new_pos[(size_t)m_global * 3 + 2];
  const float snew = (cx * cx + cy * cy) + cz * cz;

  for (int it = 0; it < NPT / 256; ++it) {
    const int n0 = it * 256 + lane * 4;
    const float4* pf4 = (const float4*)(p + (size_t)n0 * 3);
    const float4 a = pf4[0];
    const float4 bq = pf4[1];
    const float4 c = pf4[2];
    float qx[4], qy[4], qz[4];
    qx[0] = a.x;  qy[0] = a.y;  qz[0] = a.z;
    qx[1] = a.w;  qy[1] = bq.x; qz[1] = bq.y;
    qx[2] = bq.z; qy[2] = bq.w; qz[2] = c.x;
    qx[3] = c.y;  qy[3] = c.z;  qz[3] = c.w;
#pragma unroll
    for (int t = 0; t < 4; ++t) {
      const float spos = (qx[t] * qx[t] + qy[t] * qy[t]) + qz[t] * qz[t];
      const float dot = (cx * qx[t] + cy * qy[t]) + cz * qz[t];
      const float d2 = (snew + spos) - 2.0f * dot; // reference op order
      if (d2 <= 0.01f) {
        const unsigned u = __float_as_uint(d2);
        const unsigned key = (u & 0x80000000u) ? ~u : (u | 0x80000000u);
        const unsigned li = atomicAdd(&cnt[wid], 1u);
        if (li < CAP)
          list[wid][li] = ((unsigned long long)key << 32) | (unsigned)(n0 + t);
      }
    }
  }
  __syncthreads();

  int c = (int)cnt[wid];
  if (c > CAP) c = CAP;
  const int nsel = c < NSAMPLE ? c : NSAMPLE;

  for (int i = lane; i < c; i += 64) {
    const unsigned long long ki = list[wid][i];
    int rank = 0;
    for (int jj = 0; jj < c; ++jj) rank += (list[wid][jj] < ki) ? 1 : 0;
    if (rank < NSAMPLE) sel[wid][rank] = (int)(unsigned)(ki & 0xFFFFFFFFull);
  }
  __syncthreads();

  const bool active = (lane < nsel);
  const int n = sel[wid][active ? lane : 0];

  const float gpx = p[n * 3 + 0];
  const float gpy = p[n * 3 + 1];
  const float gpz = p[n * 3 + 2];
  const float gxv = xb[n];

  const float h0 = gpx - cx, h1i = gpy - cy, h2i = gpz - cz, h3i = gxv;

  float h1[32];
#pragma unroll
  for (int o = 0; o < 32; ++o) {
    float a = b1s[o];
    a += h0 * w1s[0 * 32 + o];
    a += h1i * w1s[1 * 32 + o];
    a += h2i * w1s[2 * 32 + o];
    a += h3i * w1s[3 * 32 + o];
    h1[o] = fmaxf(a, 0.0f);
  }

  float acc[32];
#pragma unroll
  for (int o = 0; o < 32; ++o) acc[o] = b2s[o];
  for (int k = 0; k < 32; ++k) {
    const float hk = h1[k];
    const float4* row = (const float4*)&w2s[k * 32];
#pragma unroll
    for (int q = 0; q < 8; ++q) {
      const float4 ww = row[q];
      acc[4 * q + 0] += hk * ww.x;
      acc[4 * q + 1] += hk * ww.y;
      acc[4 * q + 2] += hk * ww.z;
      acc[4 * q + 3] += hk * ww.w;
    }
  }
#pragma unroll
  for (int o = 0; o < 32; ++o) h1[o] = fmaxf(acc[o], 0.0f);

#pragma unroll
  for (int o = 0; o < 32; ++o) acc[o] = b3s[o];
  for (int k = 0; k < 32; ++k) {
    const float hk = h1[k];
    const float4* row = (const float4*)&w3s[k * 32];
#pragma unroll
    for (int q = 0; q < 8; ++q) {
      const float4 ww = row[q];
      acc[4 * q + 0] += hk * ww.x;
      acc[4 * q + 1] += hk * ww.y;
      acc[4 * q + 2] += hk * ww.z;
      acc[4 * q + 3] += hk * ww.w;
    }
  }
#pragma unroll
  for (int o = 0; o < 32; ++o)
    acc[o] = active ? fmaxf(acc[o], 0.0f) : -INFINITY;

#pragma unroll
  for (int mask = 1; mask <= 16; mask <<= 1) {
#pragma unroll
    for (int o = 0; o < 32; ++o)
      acc[o] = fmaxf(acc[o], __shfl_xor(acc[o], mask, 64));
  }

  if (lane == 0) {
    float4* o4 = (float4*)(out + (size_t)m_global * 32);
#pragma unroll
    for (int q = 0; q < 8; ++q)
      o4[q] = make_float4(acc[4 * q + 0], acc[4 * q + 1], acc[4 * q + 2],
                          acc[4 * q + 3]);
  }
}

// ---------------------------------------------------------------------------
extern "C" void kernel_launch(void* const* d_in, const int* in_sizes, int n_in,
                              void* d_out, int out_size, void* d_ws,
                              size_t ws_size, hipStream_t stream) {
  const float* pos = (const float*)d_in[0];
  const float* x = (const float*)d_in[1];
  const float* W1 = (const float*)d_in[2];
  const float* b1 = (const float*)d_in[3];
  const float* W2 = (const float*)d_in[4];
  const float* b2 = (const float*)d_in[5];
  const float* W3 = (const float*)d_in[6];
  const float* b3 = (const float*)d_in[7];
  float* out = (float*)d_out;
  float* new_pos = (float*)d_ws; // NB*NPOINT*3 floats = 48 KiB

  fps_kernel<<<NB, FPS_T, 0, stream>>>(pos, new_pos);
  bq_mlp_kernel<<<(NB * NPOINT) / BQ_WAVES, 256, 0, stream>>>(
      pos, x, W1, b1, W2, b2, W3, b3, new_pos, out);
}